// Round 11
// baseline (1258.435 us; speedup 1.0000x reference)
//
#include <hip/hip_runtime.h>
#include <hip/hip_bf16.h>
#include <cstdint>

using bf16 = __hip_bfloat16;

typedef __bf16 bf16x8_t __attribute__((ext_vector_type(8)));
typedef float f32x4_t __attribute__((ext_vector_type(4)));
typedef unsigned short u16x8 __attribute__((ext_vector_type(8)));

enum { EPI_BF16 = 0, EPI_QKV = 2, EPI_RELU = 4 };

__device__ __forceinline__ unsigned short f2bf_bits(float f) {
    bf16 h = __float2bfloat16(f);
    return *reinterpret_cast<unsigned short*>(&h);
}
__device__ __forceinline__ float bfbits2f(unsigned short u) {
    return __uint_as_float(((unsigned)u) << 16);
}
__device__ __forceinline__ void gload16(const void* g, void* l) {
    __builtin_amdgcn_global_load_lds(
        (const __attribute__((address_space(1))) void*)g,
        (__attribute__((address_space(3))) void*)l, 16, 0, 0);
}

// ---------------------------------------------------------------------------
// Batched weight transpose + fp32->bf16 for TWO tensors (z-switch):
// z < nz0 -> W0 slice z; else W1 slice z-nz0.  W[b][K][N] -> Wt[b][N][K]
// ---------------------------------------------------------------------------
__global__ __launch_bounds__(256) void wtrans2_kernel(
    const float* __restrict__ W0, bf16* __restrict__ T0, int nz0,
    const float* __restrict__ W1, bf16* __restrict__ T1, int Kd, int Nd) {
    __shared__ float tile[32][33];
    int b = blockIdx.z;
    const float* Wb;
    bf16* Tb;
    if (b < nz0) {
        Wb = W0 + (size_t)b * Kd * Nd;
        Tb = T0 + (size_t)b * Kd * Nd;
    } else {
        Wb = W1 + (size_t)(b - nz0) * Kd * Nd;
        Tb = T1 + (size_t)(b - nz0) * Kd * Nd;
    }
    const int n0 = blockIdx.x * 32, k0 = blockIdx.y * 32;
    const int tx = threadIdx.x, ty = threadIdx.y;
#pragma unroll
    for (int i = 0; i < 32; i += 8)
        tile[ty + i][tx] = Wb[(size_t)(k0 + ty + i) * Nd + n0 + tx];
    __syncthreads();
#pragma unroll
    for (int i = 0; i < 32; i += 8)
        Tb[(size_t)(n0 + ty + i) * Kd + k0 + tx] = __float2bfloat16(tile[tx][ty + i]);
}

// ---------------------------------------------------------------------------
// fp32 -> bf16 cast, 4 elems/thread
// ---------------------------------------------------------------------------
__global__ __launch_bounds__(256) void cast_kernel(
    const float* __restrict__ x, bf16* __restrict__ ob) {
    const int i = blockIdx.x * 256 + threadIdx.x;
    float4 v = ((const float4*)x)[i];
    uint2 pk;
    pk.x = ((unsigned)f2bf_bits(v.y) << 16) | f2bf_bits(v.x);
    pk.y = ((unsigned)f2bf_bits(v.w) << 16) | f2bf_bits(v.z);
    ((uint2*)ob)[i] = pk;
}

// ---------------------------------------------------------------------------
// NT GEMM:  C[M,N] = A[M,K] * Bt[N,K]^T (+bias) with epilogues.
// bf16 in, fp32 MFMA accum. NT threads = NT/64 waves in WM x WN grid. BK=64.
// 2-phase DOUBLE-BUFFERED K-loop: STAGE(next) || COMPUTE(cur). T2 swizzle
// via rule-21 (linear LDS dest, XOR'd global src slot, XOR'd read).
// NO setprio here: barrier-synced lockstep waves (m190: setprio hurts GEMM).
// Epilogue: acc frags -> LDS tile (XOR-swizzled, reusing staging LDS) ->
// coalesced 16B global stores. V-blocks (EPI_QKV, bcol >= vcol0, uniform per
// block) store the LDS tile TRANSPOSED so V^T global store is coalesced.
// blockIdx.z batches over weights/outputs via oBz/oCz/oCvz/oBiasz.
// ---------------------------------------------------------------------------
template <int BM, int BN, int EPI, bool HASBIAS, int NT = 256, int WM = 2, int WN = 2>
__global__ __launch_bounds__(NT) void gemm_nt(
    const bf16* __restrict__ A, const bf16* __restrict__ B,
    const float* __restrict__ bias, void* __restrict__ Cout, void* __restrict__ Caux,
    int K, int ldA, int ldB, int ldC, int vcol0,
    long long oBz, long long oCz, long long oCvz, long long oBiasz) {
    static_assert(BM % 32 == 0 && BN % 32 == 0, "tile");
    static_assert(WM * WN == NT / 64, "wave grid");
    constexpr int RR = NT / 8;
    static_assert(BM % RR == 0 || RR % BM == 0, "staging");
    static_assert(BN % RR == 0 || RR % BN == 0, "staging");
    constexpr int WTM = (BM / WM) / 16;
    constexpr int WTN = (BN / WN) / 16;
    constexpr int STG = 2 * (BM + BN) * 64;   // double-buffered staging elems
    constexpr int CTE = BM * BN;              // epilogue tile elems
    __shared__ alignas(16) bf16 smem[STG > CTE ? STG : CTE];
    bf16* lsA0 = smem;
    bf16* lsB0 = smem + BM * 64;
    bf16* lsA1 = smem + (BM + BN) * 64;
    bf16* lsB1 = lsA1 + BM * 64;

    const int t = threadIdx.x;
    const int lane = t & 63;
    const int wave = t >> 6;
    const int wm = wave / WN, wn = wave % WN;
    const int z = blockIdx.z;

    const int brow = blockIdx.x * BM, bcol = blockIdx.y * BN;
    const bf16* Ab = A + (size_t)brow * ldA;
    const bf16* Bb = B + (long long)z * oBz + (size_t)bcol * ldB;
    const float* biasz = HASBIAS ? bias + (long long)z * oBiasz : bias;

    const int srow = t >> 3;
    const int sdst = (t & 7) * 8;                 // linear LDS slot
    const int ssrc = ((t & 7) ^ (srow & 7)) * 8;  // swizzled global slot

    f32x4_t acc[WTM][WTN] = {};

#define GEMM_STAGE(AA, BB, kt)                                                \
    {                                                                         \
        _Pragma("unroll")                                                     \
        for (int r = 0; r < (BM + RR - 1) / RR; ++r)                          \
            gload16(Ab + (size_t)(srow + r * RR) * ldA + (kt) + ssrc,         \
                    &AA[(srow + r * RR) * 64 + sdst]);                        \
        _Pragma("unroll")                                                     \
        for (int r = 0; r < (BN + RR - 1) / RR; ++r)                          \
            gload16(Bb + (size_t)(srow + r * RR) * ldB + (kt) + ssrc,         \
                    &BB[(srow + r * RR) * 64 + sdst]);                        \
    }

#define GEMM_COMPUTE(AA, BB)                                                  \
    {                                                                         \
        _Pragma("unroll")                                                     \
        for (int ks = 0; ks < 2; ++ks) {                                      \
            bf16x8_t af[WTM], bfr[WTN];                                       \
            _Pragma("unroll")                                                 \
            for (int m = 0; m < WTM; ++m) {                                   \
                const int rowA = wm * (BM / WM) + m * 16 + (lane & 15);       \
                const int slot = ks * 4 + (lane >> 4);                        \
                af[m] = *(const bf16x8_t*)&AA[rowA * 64 + ((slot ^ (rowA & 7)) * 8)]; \
            }                                                                 \
            _Pragma("unroll")                                                 \
            for (int n = 0; n < WTN; ++n) {                                   \
                const int rowB = wn * (BN / WN) + n * 16 + (lane & 15);       \
                const int slot = ks * 4 + (lane >> 4);                        \
                bfr[n] = *(const bf16x8_t*)&BB[rowB * 64 + ((slot ^ (rowB & 7)) * 8)]; \
            }                                                                 \
            _Pragma("unroll")                                                 \
            for (int m = 0; m < WTM; ++m)                                     \
                _Pragma("unroll")                                             \
                for (int n = 0; n < WTN; ++n)                                 \
                    acc[m][n] = __builtin_amdgcn_mfma_f32_16x16x32_bf16(      \
                        af[m], bfr[n], acc[m][n], 0, 0, 0);                   \
        }                                                                     \
    }

    GEMM_STAGE(lsA0, lsB0, 0);
    __syncthreads();
    int kt = 0;
    while (true) {
        int kn = kt + 64;
        if (kn < K) GEMM_STAGE(lsA1, lsB1, kn);
        GEMM_COMPUTE(lsA0, lsB0);
        __syncthreads();
        kt = kn;
        if (kt >= K) break;
        kn = kt + 64;
        if (kn < K) GEMM_STAGE(lsA0, lsB0, kn);
        GEMM_COMPUTE(lsA1, lsB1);
        __syncthreads();
        kt = kn;
        if (kt >= K) break;
    }
#undef GEMM_STAGE
#undef GEMM_COMPUTE

    // ---- epilogue: frags -> swizzled LDS tile -> coalesced stores ----
    // C/D layout: col = lane&15, row = (lane>>4)*4 + reg  [m89/m91]
    const int lr = (lane >> 4) * 4, lc = lane & 15;
    const bool isV = (EPI == EPI_QKV) && (bcol >= vcol0);  // uniform per block
    unsigned short* cts = (unsigned short*)smem;
#pragma unroll
    for (int m = 0; m < WTM; ++m) {
        const int row0 = wm * (BM / WM) + m * 16 + lr;   // local row base
#pragma unroll
        for (int n = 0; n < WTN; ++n) {
            const int col = wn * (BN / WN) + n * 16 + lc;  // local col
            float bv = 0.f;
            if constexpr (HASBIAS) bv = biasz[bcol + col];
            unsigned short h4[4];
#pragma unroll
            for (int r = 0; r < 4; ++r) {
                float x = acc[m][n][r] + bv;
                if constexpr (EPI == EPI_RELU) x = fmaxf(x, 0.f);
                h4[r] = f2bf_bits(x);
            }
            if (isV) {
                // transposed tile: ctV[col][q], q-run of 4 contiguous (8B)
                union { unsigned short h[4]; uint2 u; } pk;
#pragma unroll
                for (int r = 0; r < 4; ++r) pk.h[r] = h4[r];
                *(uint2*)&cts[col * BM + (row0 ^ ((col & 7) << 3))] = pk.u;
            } else {
#pragma unroll
                for (int r = 0; r < 4; ++r)
                    cts[(row0 + r) * BN + (col ^ (((row0 + r) & 7) << 3))] = h4[r];
            }
        }
    }
    __syncthreads();
    if (isV) {
        bf16* Cv = (bf16*)Caux + (long long)z * oCvz;
        const int bb = brow >> 9, qb0 = brow & 511;
        for (int s = t; s < CTE / 8; s += NT) {
            const int d = s / (BM / 8), q8 = (s % (BM / 8)) * 8;
            u16x8 val = *(const u16x8*)&cts[d * BM + (q8 ^ ((d & 7) << 3))];
            *(u16x8*)&Cv[(size_t)bb * 262144 + (size_t)(bcol - vcol0 + d) * 512 + qb0 + q8] = val;
        }
    } else {
        bf16* C = (bf16*)Cout + (long long)z * oCz;
        for (int s = t; s < CTE / 8; s += NT) {
            const int row = s / (BN / 8), c8 = (s % (BN / 8)) * 8;
            u16x8 val = *(const u16x8*)&cts[row * BN + (c8 ^ ((row & 7) << 3))];
            *(u16x8*)&C[(size_t)(brow + row) * ldC + bcol + c8] = val;
        }
    }
}

// ---------------------------------------------------------------------------
// Flash attention: one block per (b*8+h, qblk). 256 threads (4 waves),
// QBLK=64 (16 q-rows/wave), KT=128 x 4 tiles, online softmax.
// Grid (64, 8): q-blocks sharing K/V have id-stride 64 == 0 mod 8 (co-XCD).
// T5 setprio around MFMA clusters (independent blocks at different phases).
// Coalesced 16B output via plds round-trip.
// ---------------------------------------------------------------------------
__global__ __launch_bounds__(256) void flash_kernel(
    const bf16* __restrict__ Q, const bf16* __restrict__ Kg,
    const bf16* __restrict__ Vt, bf16* __restrict__ O,
    int ldK, int ldO, float qscale) {
    __shared__ alignas(16) bf16 klds[128 * 64];
    __shared__ alignas(16) bf16 vlds[64 * 128];
    __shared__ alignas(16) unsigned short plds[4][16 * 136];

    const int t = threadIdx.x, lane = t & 63, w = t >> 6;
    const int bh = blockIdx.x;
    const int b = bh >> 3, h = bh & 7;
    const int qb = blockIdx.y;

    const bf16* Qb = Q + (size_t)(b * 512 + qb * 64) * 1024 + h * 64;
    const bf16* Kb = Kg + (size_t)(b * 512) * ldK + h * 64;
    const bf16* Vb = Vt + (size_t)b * 262144 + (size_t)(h * 64) * 512;

    bf16x8_t qf[2];
    {
        const bf16* qr = Qb + (size_t)(w * 16 + (lane & 15)) * 1024 + (lane >> 4) * 8;
        qf[0] = *(const bf16x8_t*)qr;
        qf[1] = *(const bf16x8_t*)(qr + 32);
    }

    f32x4_t oacc[4] = {};
    float mrow[4] = {-1e30f, -1e30f, -1e30f, -1e30f};
    float lrow[4] = {0.f, 0.f, 0.f, 0.f};

    for (int kt = 0; kt < 4; ++kt) {
#pragma unroll
        for (int rd = 0; rd < 4; ++rd) {
            const int id = t + rd * 256;
            const int kr = id >> 3, sl = id & 7;
            gload16(Kb + (size_t)(kt * 128 + kr) * ldK + ((sl ^ (kr & 7)) * 8),
                    &klds[id * 8]);
        }
#pragma unroll
        for (int rd = 0; rd < 4; ++rd) {
            const int id = t + rd * 256;
            const int dr = id >> 4, sl = id & 15;
            gload16(Vb + (size_t)dr * 512 + kt * 128 + ((sl ^ (dr & 7)) * 8),
                    &vlds[id * 8]);
        }
        __syncthreads();

        // QK^T
        f32x4_t sc[8] = {};
        __builtin_amdgcn_s_setprio(1);
#pragma unroll
        for (int kf = 0; kf < 8; ++kf) {
            const int krow = kf * 16 + (lane & 15);
#pragma unroll
            for (int ks = 0; ks < 2; ++ks) {
                const int slot = (ks * 4 + (lane >> 4)) ^ (krow & 7);
                bf16x8_t kfr = *(const bf16x8_t*)&klds[krow * 64 + slot * 8];
                sc[kf] = __builtin_amdgcn_mfma_f32_16x16x32_bf16(qf[ks], kfr, sc[kf], 0, 0, 0);
            }
        }
        __builtin_amdgcn_s_setprio(0);
        // online softmax
        float tm[4] = {-1e30f, -1e30f, -1e30f, -1e30f};
#pragma unroll
        for (int kf = 0; kf < 8; ++kf)
#pragma unroll
            for (int r = 0; r < 4; ++r) {
                sc[kf][r] *= qscale;
                tm[r] = fmaxf(tm[r], sc[kf][r]);
            }
#pragma unroll
        for (int mm = 1; mm < 16; mm <<= 1)
#pragma unroll
            for (int r = 0; r < 4; ++r) tm[r] = fmaxf(tm[r], __shfl_xor(tm[r], mm, 64));
        float mnew[4], scal[4], ts[4] = {0.f, 0.f, 0.f, 0.f};
#pragma unroll
        for (int r = 0; r < 4; ++r) {
            mnew[r] = fmaxf(mrow[r], tm[r]);
            scal[r] = __expf(mrow[r] - mnew[r]);
            mrow[r] = mnew[r];
        }
#pragma unroll
        for (int kf = 0; kf < 8; ++kf)
#pragma unroll
            for (int r = 0; r < 4; ++r) {
                const float p = __expf(sc[kf][r] - mnew[r]);
                ts[r] += p;
                plds[w][((lane >> 4) * 4 + r) * 136 + kf * 16 + (lane & 15)] = f2bf_bits(p);
            }
#pragma unroll
        for (int mm = 1; mm < 16; mm <<= 1)
#pragma unroll
            for (int r = 0; r < 4; ++r) ts[r] += __shfl_xor(ts[r], mm, 64);
#pragma unroll
        for (int r = 0; r < 4; ++r) lrow[r] = lrow[r] * scal[r] + ts[r];
#pragma unroll
        for (int n = 0; n < 4; ++n)
#pragma unroll
            for (int r = 0; r < 4; ++r) oacc[n][r] *= scal[r];
        // PV
        __builtin_amdgcn_s_setprio(1);
#pragma unroll
        for (int ks2 = 0; ks2 < 4; ++ks2) {
            bf16x8_t pa =
                *(const bf16x8_t*)&plds[w][(lane & 15) * 136 + ks2 * 32 + (lane >> 4) * 8];
#pragma unroll
            for (int n = 0; n < 4; ++n) {
                const int drow = n * 16 + (lane & 15);
                const int slot = (ks2 * 4 + (lane >> 4)) ^ (drow & 7);
                bf16x8_t vbf = *(const bf16x8_t*)&vlds[drow * 128 + slot * 8];
                oacc[n] = __builtin_amdgcn_mfma_f32_16x16x32_bf16(pa, vbf, oacc[n], 0, 0, 0);
            }
        }
        __builtin_amdgcn_s_setprio(0);
        __syncthreads();
    }
    // epilogue: out = oacc / l, via plds for coalesced 16B stores
#pragma unroll
    for (int r = 0; r < 4; ++r) {
        const float inv = 1.0f / lrow[r];
#pragma unroll
        for (int n = 0; n < 4; ++n)
            plds[w][((lane >> 4) * 4 + r) * 136 + n * 16 + (lane & 15)] =
                f2bf_bits(oacc[n][r] * inv);
    }
    __syncthreads();
    {
        bf16* Ob = O + (size_t)(b * 512 + qb * 64 + w * 16) * ldO + h * 64;
#pragma unroll
        for (int it = 0; it < 2; ++it) {
            const int seg = lane + it * 64;
            const int row = seg >> 3, c8 = (seg & 7) * 8;
            u16x8 val = *(const u16x8*)&plds[w][row * 136 + c8];
            *(u16x8*)&Ob[(size_t)row * ldO + c8] = val;
        }
    }
}

// ---------------------------------------------------------------------------
// out = LN(x + a) * alpha + beta (unbiased std, no eps). One wave per row.
// x, a bf16; output bf16 (ob) and/or fp32 (of).
// ---------------------------------------------------------------------------
__global__ __launch_bounds__(256) void add_ln_kernel(
    const bf16* __restrict__ a, const bf16* __restrict__ x,
    const float* __restrict__ alpha, const float* __restrict__ beta,
    float* __restrict__ of, bf16* __restrict__ ob) {
    const int row = blockIdx.x * 4 + (threadIdx.x >> 6);
    const int lane = threadIdx.x & 63;
    const size_t base = (size_t)row * 512 + lane * 8;
    float v[8];
    {
        u16x8 ux = *(const u16x8*)(x + base);
#pragma unroll
        for (int j = 0; j < 8; ++j) v[j] = bfbits2f(ux[j]);
    }
    if (a) {
        u16x8 ua = *(const u16x8*)(a + base);
#pragma unroll
        for (int j = 0; j < 8; ++j) v[j] += bfbits2f(ua[j]);
    }
    float s = 0.f, ss = 0.f;
#pragma unroll
    for (int j = 0; j < 8; ++j) { s += v[j]; ss += v[j] * v[j]; }
#pragma unroll
    for (int m = 1; m < 64; m <<= 1) {
        s += __shfl_xor(s, m, 64);
        ss += __shfl_xor(ss, m, 64);
    }
    const float mean = s * (1.0f / 512.0f);
    const float var = (ss - s * mean) * (1.0f / 511.0f);
    const float rstd = rsqrtf(var);
    const int col = lane * 8;
    const float4* alp = (const float4*)(alpha + col);
    const float4* bep = (const float4*)(beta + col);
    float4 al0 = alp[0], al1 = alp[1], be0 = bep[0], be1 = bep[1];
    float al[8] = {al0.x, al0.y, al0.z, al0.w, al1.x, al1.y, al1.z, al1.w};
    float be[8] = {be0.x, be0.y, be0.z, be0.w, be1.x, be1.y, be1.z, be1.w};
    float y[8];
#pragma unroll
    for (int j = 0; j < 8; ++j) y[j] = (v[j] - mean) * rstd * al[j] + be[j];
    if (ob) {
        u16x8 u;
#pragma unroll
        for (int j = 0; j < 8; ++j) u[j] = f2bf_bits(y[j]);
        *(u16x8*)(ob + base) = u;
    }
    if (of) {
        float4 o0, o1;
        o0.x = y[0]; o0.y = y[1]; o0.z = y[2]; o0.w = y[3];
        o1.x = y[4]; o1.y = y[5]; o1.z = y[6]; o1.w = y[7];
        float4* op = (float4*)(of + base);
        op[0] = o0; op[1] = o1;
    }
}

// ---------------------------------------------------------------------------
extern "C" void kernel_launch(void* const* d_in, const int* in_sizes, int n_in,
                              void* d_out, int out_size, void* d_ws, size_t ws_size,
                              hipStream_t stream) {
    (void)in_sizes; (void)n_in; (void)out_size;

    const float* in_enc = (const float*)d_in[0];
    const float* in_dec = (const float*)d_in[1];
    const float* enc_W  = (const float*)d_in[2];
    const float* enc_b  = (const float*)d_in[3];
    const float* enc_W1 = (const float*)d_in[4];
    const float* enc_b1 = (const float*)d_in[5];
    const float* enc_W2 = (const float*)d_in[6];
    const float* enc_b2 = (const float*)d_in[7];
    const float* enc_al = (const float*)d_in[8];
    const float* enc_be = (const float*)d_in[9];
    const float* dec_W  = (const float*)d_in[10];
    const float* dec_b  = (const float*)d_in[11];
    const float* dec_W1 = (const float*)d_in[12];
    const float* dec_b1 = (const float*)d_in[13];
    const float* dec_W2 = (const float*)d_in[14];
    const float* dec_b2 = (const float*)d_in[15];
    const float* dec_al = (const float*)d_in[16];
    const float* dec_be = (const float*)d_in[17];
    const float* fin_al = (const float*)d_in[18];
    const float* fin_be = (const float*)d_in[19];

    constexpr int Dm = 512, FFm = 2048, Lm = 6;
    constexpr int M = 4096;  // B*S
    const size_t DD = (size_t)Dm * Dm;
    const size_t DFF = (size_t)Dm * FFm;
    const long long MD = (long long)M * Dm;  // 2097152
    const float QSCALE = 0.04419417382415922f;  // 1/sqrt(512)

    char* wsp = (char*)d_ws;
    auto alloc = [&](size_t bytes) -> char* {
        char* p = wsp;
        wsp += (bytes + 255) & ~(size_t)255;
        return p;
    };

    bf16* wtEncW  = (bf16*)alloc(sizeof(bf16) * 24 * DD);
    bf16* wtEncW1 = (bf16*)alloc(sizeof(bf16) * 6 * DFF);
    bf16* wtEncW2 = (bf16*)alloc(sizeof(bf16) * 6 * DFF);
    bf16* wtDecW  = (bf16*)alloc(sizeof(bf16) * 48 * DD);
    bf16* wtDecW1 = (bf16*)alloc(sizeof(bf16) * 6 * DFF);
    bf16* wtDecW2 = (bf16*)alloc(sizeof(bf16) * 6 * DFF);
    bf16* qkvbuf = (bf16*)alloc(sizeof(bf16) * M * 1024);  // Q cols 0..511; K / attn-out cols 512..1023
    bf16* vt     = (bf16*)alloc(sizeof(bf16) * M * Dm);    // self V^T [b][d][k]
    bf16* ckbuf  = (bf16*)alloc(sizeof(bf16) * M * Dm);    // self-attn out
    bf16* ck6    = (bf16*)alloc(sizeof(bf16) * 6 * M * Dm);  // cross K, all layers
    bf16* cv6    = (bf16*)alloc(sizeof(bf16) * 6 * M * Dm);  // cross V^T, all layers
    bf16* ffnmid = (bf16*)alloc(sizeof(bf16) * M * FFm);
    bf16* projb  = (bf16*)alloc(sizeof(bf16) * M * Dm);    // residual branch
    bf16* zAb = (bf16*)alloc(sizeof(bf16) * M * Dm);
    bf16* zBb = (bf16*)alloc(sizeof(bf16) * M * Dm);
    bf16* zCb = (bf16*)alloc(sizeof(bf16) * M * Dm);       // decoder input (pre-cast)
    bf16* zencb = (bf16*)alloc(sizeof(bf16) * M * Dm);

    if ((size_t)(wsp - (char*)d_ws) > ws_size) return;

    // ---- one-time prep: weight transpose (batched) + input casts ----
    {
        dim3 bl(32, 8);
        wtrans2_kernel<<<dim3(Dm / 32, Dm / 32, 72), bl, 0, stream>>>(
            enc_W, wtEncW, 24, dec_W, wtDecW, Dm, Dm);
        wtrans2_kernel<<<dim3(FFm / 32, Dm / 32, 12), bl, 0, stream>>>(
            enc_W1, wtEncW1, 6, dec_W1, wtDecW1, Dm, FFm);
        wtrans2_kernel<<<dim3(Dm / 32, FFm / 32, 12), bl, 0, stream>>>(
            enc_W2, wtEncW2, 6, dec_W2, wtDecW2, FFm, Dm);
        cast_kernel<<<2048, 256, 0, stream>>>(in_enc, zAb);
        cast_kernel<<<2048, 256, 0, stream>>>(in_dec, zCb);
    }

    bf16* curB = zAb;
    bf16* othB = zBb;
    auto swapbuf = [&]() { bf16* tb = curB; curB = othB; othB = tb; };

    // self-attention: fused QKV proj (V -> vt transposed), flash, outproj
    auto self_attention = [&](const bf16* src, const bf16* Wt4, const float* b4) {
        gemm_nt<64, 128, EPI_QKV, true, 256, 1, 4><<<dim3(64, 12, 1), 256, 0, stream>>>(
            src, Wt4, b4, qkvbuf, vt, Dm, Dm, Dm, 1024, 1024, 0, 0, 0, 0);
        flash_kernel<<<dim3(64, 8), 256, 0, stream>>>(
            qkvbuf, qkvbuf + 512, vt, ckbuf, 1024, 512, QSCALE);
        gemm_nt<64, 64, EPI_BF16, true, 256, 2, 2><<<dim3(64, 8, 1), 256, 0, stream>>>(
            ckbuf, Wt4 + 3 * DD, b4 + 3 * Dm, projb, nullptr, Dm, 512, Dm, Dm, 0,
            0, 0, 0, 0);
    };

    // cross-attention layer i: Q proj, flash vs precomputed ck6/cv6, outproj
    auto cross_attention = [&](const bf16* src, const bf16* Wt4, const float* b4, int i) {
        gemm_nt<64, 64, EPI_BF16, true, 256, 2, 2><<<dim3(64, 8, 1), 256, 0, stream>>>(
            src, Wt4, b4, qkvbuf, nullptr, Dm, Dm, Dm, 1024, 0, 0, 0, 0, 0);
        flash_kernel<<<dim3(64, 8), 256, 0, stream>>>(
            qkvbuf, ck6 + (long long)i * MD, cv6 + (long long)i * MD, qkvbuf + 512,
            512, 1024, QSCALE);
        gemm_nt<64, 64, EPI_BF16, true, 256, 2, 2><<<dim3(64, 8, 1), 256, 0, stream>>>(
            qkvbuf + 512, Wt4 + 3 * DD, b4 + 3 * Dm, projb, nullptr, Dm, 1024, Dm, Dm, 0,
            0, 0, 0, 0);
    };

    auto ffn = [&](const bf16* src, const bf16* W1t, const float* b1v,
                   const bf16* W2t, const float* b2v) {
        gemm_nt<128, 128, EPI_RELU, true, 512, 2, 4><<<dim3(32, 16, 1), 512, 0, stream>>>(
            src, W1t, b1v, ffnmid, nullptr, Dm, Dm, Dm, FFm, 0, 0, 0, 0, 0);
        gemm_nt<64, 64, EPI_BF16, true, 256, 2, 2><<<dim3(64, 8, 1), 256, 0, stream>>>(
            ffnmid, W2t, b2v, projb, nullptr, FFm, FFm, FFm, Dm, 0, 0, 0, 0, 0);
    };

    // ================= encoder =================
    for (int i = 0; i < Lm; ++i) {
        self_attention(curB, wtEncW + (size_t)i * 4 * DD, enc_b + (size_t)i * 4 * Dm);
        add_ln_kernel<<<1024, 256, 0, stream>>>(
            projb, curB, enc_al + (size_t)(i * 2) * Dm, enc_be + (size_t)(i * 2) * Dm,
            nullptr, othB);
        swapbuf();
        ffn(curB, wtEncW1 + (size_t)i * DFF, enc_b1 + (size_t)i * FFm,
            wtEncW2 + (size_t)i * DFF, enc_b2 + (size_t)i * Dm);
        add_ln_kernel<<<1024, 256, 0, stream>>>(
            projb, curB, enc_al + (size_t)(i * 2 + 1) * Dm, enc_be + (size_t)(i * 2 + 1) * Dm,
            nullptr, othB);
        swapbuf();
    }
    add_ln_kernel<<<1024, 256, 0, stream>>>(nullptr, curB, fin_al, fin_be, nullptr, zencb);

    // Precompute cross K/V for ALL 6 decoder layers in one batched GEMM.
    gemm_nt<128, 128, EPI_QKV, true, 512, 2, 4><<<dim3(32, 8, 6), 512, 0, stream>>>(
        zencb, wtDecW + 5 * DD, dec_b + 5 * Dm, ck6, cv6, Dm, Dm, Dm, 512, 512,
        /*oBz=*/8LL * (long long)DD, /*oCz=*/MD, /*oCvz=*/MD, /*oBiasz=*/8LL * Dm);

    // ================= decoder =================
    curB = zCb; othB = zBb;
    for (int i = 0; i < Lm; ++i) {
        self_attention(curB, wtDecW + (size_t)(i * 2 + 0) * 4 * DD,
                       dec_b + (size_t)(i * 2 + 0) * 4 * Dm);
        add_ln_kernel<<<1024, 256, 0, stream>>>(
            projb, curB, dec_al + (size_t)(i * 3 + 0) * Dm, dec_be + (size_t)(i * 3 + 0) * Dm,
            nullptr, othB);
        if (curB == zCb) { curB = othB; othB = zAb; }
        else swapbuf();
        cross_attention(curB, wtDecW + (size_t)(i * 2 + 1) * 4 * DD,
                        dec_b + (size_t)(i * 2 + 1) * 4 * Dm, i);
        add_ln_kernel<<<1024, 256, 0, stream>>>(
            projb, curB, dec_al + (size_t)(i * 3 + 1) * Dm, dec_be + (size_t)(i * 3 + 1) * Dm,
            nullptr, othB);
        swapbuf();
        ffn(curB, wtDecW1 + (size_t)i * DFF, dec_b1 + (size_t)i * FFm,
            wtDecW2 + (size_t)i * DFF, dec_b2 + (size_t)i * Dm);
        add_ln_kernel<<<1024, 256, 0, stream>>>(
            projb, curB, dec_al + (size_t)(i * 3 + 2) * Dm, dec_be + (size_t)(i * 3 + 2) * Dm,
            nullptr, othB);
        swapbuf();
    }
    add_ln_kernel<<<1024, 256, 0, stream>>>(nullptr, curB, fin_al + Dm, fin_be + Dm,
                                            (float*)d_out, nullptr);
}

// Round 12
// 1250.353 us; speedup vs baseline: 1.0065x; 1.0065x over previous
//
#include <hip/hip_runtime.h>
#include <hip/hip_bf16.h>
#include <cstdint>

using bf16 = __hip_bfloat16;

typedef __bf16 bf16x8_t __attribute__((ext_vector_type(8)));
typedef float f32x4_t __attribute__((ext_vector_type(4)));
typedef unsigned short u16x8 __attribute__((ext_vector_type(8)));

enum { EPI_BF16 = 0, EPI_QKV = 2, EPI_RELU = 4 };

__device__ __forceinline__ unsigned short f2bf_bits(float f) {
    bf16 h = __float2bfloat16(f);
    return *reinterpret_cast<unsigned short*>(&h);
}
__device__ __forceinline__ float bfbits2f(unsigned short u) {
    return __uint_as_float(((unsigned)u) << 16);
}
__device__ __forceinline__ void gload16(const void* g, void* l) {
    __builtin_amdgcn_global_load_lds(
        (const __attribute__((address_space(1))) void*)g,
        (__attribute__((address_space(3))) void*)l, 16, 0, 0);
}

// ---------------------------------------------------------------------------
// Batched weight transpose + fp32->bf16 for TWO tensors (z-switch):
// z < nz0 -> W0 slice z; else W1 slice z-nz0.  W[b][K][N] -> Wt[b][N][K]
// ---------------------------------------------------------------------------
__global__ __launch_bounds__(256) void wtrans2_kernel(
    const float* __restrict__ W0, bf16* __restrict__ T0, int nz0,
    const float* __restrict__ W1, bf16* __restrict__ T1, int Kd, int Nd) {
    __shared__ float tile[32][33];
    int b = blockIdx.z;
    const float* Wb;
    bf16* Tb;
    if (b < nz0) {
        Wb = W0 + (size_t)b * Kd * Nd;
        Tb = T0 + (size_t)b * Kd * Nd;
    } else {
        Wb = W1 + (size_t)(b - nz0) * Kd * Nd;
        Tb = T1 + (size_t)(b - nz0) * Kd * Nd;
    }
    const int n0 = blockIdx.x * 32, k0 = blockIdx.y * 32;
    const int tx = threadIdx.x, ty = threadIdx.y;
#pragma unroll
    for (int i = 0; i < 32; i += 8)
        tile[ty + i][tx] = Wb[(size_t)(k0 + ty + i) * Nd + n0 + tx];
    __syncthreads();
#pragma unroll
    for (int i = 0; i < 32; i += 8)
        Tb[(size_t)(n0 + ty + i) * Kd + k0 + tx] = __float2bfloat16(tile[tx][ty + i]);
}

// ---------------------------------------------------------------------------
// fp32 -> bf16 cast, 4 elems/thread
// ---------------------------------------------------------------------------
__global__ __launch_bounds__(256) void cast_kernel(
    const float* __restrict__ x, bf16* __restrict__ ob) {
    const int i = blockIdx.x * 256 + threadIdx.x;
    float4 v = ((const float4*)x)[i];
    uint2 pk;
    pk.x = ((unsigned)f2bf_bits(v.y) << 16) | f2bf_bits(v.x);
    pk.y = ((unsigned)f2bf_bits(v.w) << 16) | f2bf_bits(v.z);
    ((uint2*)ob)[i] = pk;
}

// ---------------------------------------------------------------------------
// NT GEMM:  C[M,N] = A[M,K] * Bt[N,K]^T (+bias) with epilogues.
// bf16 in, fp32 MFMA accum. NT threads = NT/64 waves in WM x WN grid. BK=64.
// 2-phase DOUBLE-BUFFERED K-loop: STAGE(next) || COMPUTE(cur). T2 swizzle
// via rule-21 (linear LDS dest, XOR'd global src slot, XOR'd read).
// NO setprio here: barrier-synced lockstep waves (m190: setprio hurts GEMM).
// Epilogue: acc frags -> LDS tile (XOR-swizzled, reusing staging LDS) ->
// coalesced 16B global stores. V-blocks (EPI_QKV, bcol >= vcol0, uniform per
// block) store the LDS tile TRANSPOSED so V^T global store is coalesced.
// blockIdx.z batches over weights/outputs via oBz/oCz/oCvz/oBiasz.
// ---------------------------------------------------------------------------
template <int BM, int BN, int EPI, bool HASBIAS, int NT = 256, int WM = 2, int WN = 2>
__global__ __launch_bounds__(NT) void gemm_nt(
    const bf16* __restrict__ A, const bf16* __restrict__ B,
    const float* __restrict__ bias, void* __restrict__ Cout, void* __restrict__ Caux,
    int K, int ldA, int ldB, int ldC, int vcol0,
    long long oBz, long long oCz, long long oCvz, long long oBiasz) {
    static_assert(BM % 32 == 0 && BN % 32 == 0, "tile");
    static_assert(WM * WN == NT / 64, "wave grid");
    constexpr int RR = NT / 8;
    static_assert(BM % RR == 0 || RR % BM == 0, "staging");
    static_assert(BN % RR == 0 || RR % BN == 0, "staging");
    constexpr int WTM = (BM / WM) / 16;
    constexpr int WTN = (BN / WN) / 16;
    constexpr int STG = 2 * (BM + BN) * 64;   // double-buffered staging elems
    constexpr int CTE = BM * BN;              // epilogue tile elems
    __shared__ alignas(16) bf16 smem[STG > CTE ? STG : CTE];
    bf16* lsA0 = smem;
    bf16* lsB0 = smem + BM * 64;
    bf16* lsA1 = smem + (BM + BN) * 64;
    bf16* lsB1 = lsA1 + BM * 64;

    const int t = threadIdx.x;
    const int lane = t & 63;
    const int wave = t >> 6;
    const int wm = wave / WN, wn = wave % WN;
    const int z = blockIdx.z;

    const int brow = blockIdx.x * BM, bcol = blockIdx.y * BN;
    const bf16* Ab = A + (size_t)brow * ldA;
    const bf16* Bb = B + (long long)z * oBz + (size_t)bcol * ldB;
    const float* biasz = HASBIAS ? bias + (long long)z * oBiasz : bias;

    const int srow = t >> 3;
    const int sdst = (t & 7) * 8;                 // linear LDS slot
    const int ssrc = ((t & 7) ^ (srow & 7)) * 8;  // swizzled global slot

    f32x4_t acc[WTM][WTN] = {};

#define GEMM_STAGE(AA, BB, kt)                                                \
    {                                                                         \
        _Pragma("unroll")                                                     \
        for (int r = 0; r < (BM + RR - 1) / RR; ++r)                          \
            gload16(Ab + (size_t)(srow + r * RR) * ldA + (kt) + ssrc,         \
                    &AA[(srow + r * RR) * 64 + sdst]);                        \
        _Pragma("unroll")                                                     \
        for (int r = 0; r < (BN + RR - 1) / RR; ++r)                          \
            gload16(Bb + (size_t)(srow + r * RR) * ldB + (kt) + ssrc,         \
                    &BB[(srow + r * RR) * 64 + sdst]);                        \
    }

#define GEMM_COMPUTE(AA, BB)                                                  \
    {                                                                         \
        _Pragma("unroll")                                                     \
        for (int ks = 0; ks < 2; ++ks) {                                      \
            bf16x8_t af[WTM], bfr[WTN];                                       \
            _Pragma("unroll")                                                 \
            for (int m = 0; m < WTM; ++m) {                                   \
                const int rowA = wm * (BM / WM) + m * 16 + (lane & 15);       \
                const int slot = ks * 4 + (lane >> 4);                        \
                af[m] = *(const bf16x8_t*)&AA[rowA * 64 + ((slot ^ (rowA & 7)) * 8)]; \
            }                                                                 \
            _Pragma("unroll")                                                 \
            for (int n = 0; n < WTN; ++n) {                                   \
                const int rowB = wn * (BN / WN) + n * 16 + (lane & 15);       \
                const int slot = ks * 4 + (lane >> 4);                        \
                bfr[n] = *(const bf16x8_t*)&BB[rowB * 64 + ((slot ^ (rowB & 7)) * 8)]; \
            }                                                                 \
            _Pragma("unroll")                                                 \
            for (int m = 0; m < WTM; ++m)                                     \
                _Pragma("unroll")                                             \
                for (int n = 0; n < WTN; ++n)                                 \
                    acc[m][n] = __builtin_amdgcn_mfma_f32_16x16x32_bf16(      \
                        af[m], bfr[n], acc[m][n], 0, 0, 0);                   \
        }                                                                     \
    }

    GEMM_STAGE(lsA0, lsB0, 0);
    __syncthreads();
    int kt = 0;
    while (true) {
        int kn = kt + 64;
        if (kn < K) GEMM_STAGE(lsA1, lsB1, kn);
        GEMM_COMPUTE(lsA0, lsB0);
        __syncthreads();
        kt = kn;
        if (kt >= K) break;
        kn = kt + 64;
        if (kn < K) GEMM_STAGE(lsA0, lsB0, kn);
        GEMM_COMPUTE(lsA1, lsB1);
        __syncthreads();
        kt = kn;
        if (kt >= K) break;
    }
#undef GEMM_STAGE
#undef GEMM_COMPUTE

    // ---- epilogue: frags -> swizzled LDS tile -> coalesced stores ----
    // C/D layout: col = lane&15, row = (lane>>4)*4 + reg  [m89/m91]
    const int lr = (lane >> 4) * 4, lc = lane & 15;
    const bool isV = (EPI == EPI_QKV) && (bcol >= vcol0);  // uniform per block
    unsigned short* cts = (unsigned short*)smem;
#pragma unroll
    for (int m = 0; m < WTM; ++m) {
        const int row0 = wm * (BM / WM) + m * 16 + lr;   // local row base
#pragma unroll
        for (int n = 0; n < WTN; ++n) {
            const int col = wn * (BN / WN) + n * 16 + lc;  // local col
            float bv = 0.f;
            if constexpr (HASBIAS) bv = biasz[bcol + col];
            unsigned short h4[4];
#pragma unroll
            for (int r = 0; r < 4; ++r) {
                float x = acc[m][n][r] + bv;
                if constexpr (EPI == EPI_RELU) x = fmaxf(x, 0.f);
                h4[r] = f2bf_bits(x);
            }
            if (isV) {
                // transposed tile: ctV[col][q], q-run of 4 contiguous (8B)
                union { unsigned short h[4]; uint2 u; } pk;
#pragma unroll
                for (int r = 0; r < 4; ++r) pk.h[r] = h4[r];
                *(uint2*)&cts[col * BM + (row0 ^ ((col & 7) << 3))] = pk.u;
            } else {
#pragma unroll
                for (int r = 0; r < 4; ++r)
                    cts[(row0 + r) * BN + (col ^ (((row0 + r) & 7) << 3))] = h4[r];
            }
        }
    }
    __syncthreads();
    if (isV) {
        bf16* Cv = (bf16*)Caux + (long long)z * oCvz;
        const int bb = brow >> 9, qb0 = brow & 511;
        for (int s = t; s < CTE / 8; s += NT) {
            const int d = s / (BM / 8), q8 = (s % (BM / 8)) * 8;
            u16x8 val = *(const u16x8*)&cts[d * BM + (q8 ^ ((d & 7) << 3))];
            *(u16x8*)&Cv[(size_t)bb * 262144 + (size_t)(bcol - vcol0 + d) * 512 + qb0 + q8] = val;
        }
    } else {
        bf16* C = (bf16*)Cout + (long long)z * oCz;
        for (int s = t; s < CTE / 8; s += NT) {
            const int row = s / (BN / 8), c8 = (s % (BN / 8)) * 8;
            u16x8 val = *(const u16x8*)&cts[row * BN + (c8 ^ ((row & 7) << 3))];
            *(u16x8*)&C[(size_t)(brow + row) * ldC + bcol + c8] = val;
        }
    }
}

// ---------------------------------------------------------------------------
// Flash attention: one block per (b*8+h, qblk). 256 threads (4 waves),
// QBLK=64 (16 q-rows/wave), KT=128 x 4 tiles, online softmax.
// Grid (64, 8): q-blocks sharing K/V have id-stride 64 == 0 mod 8 (co-XCD).
// T5 setprio around MFMA clusters (independent blocks at different phases).
// Coalesced 16B output via plds round-trip.
// ---------------------------------------------------------------------------
__global__ __launch_bounds__(256) void flash_kernel(
    const bf16* __restrict__ Q, const bf16* __restrict__ Kg,
    const bf16* __restrict__ Vt, bf16* __restrict__ O,
    int ldK, int ldO, float qscale) {
    __shared__ alignas(16) bf16 klds[128 * 64];
    __shared__ alignas(16) bf16 vlds[64 * 128];
    __shared__ alignas(16) unsigned short plds[4][16 * 136];

    const int t = threadIdx.x, lane = t & 63, w = t >> 6;
    const int bh = blockIdx.x;
    const int b = bh >> 3, h = bh & 7;
    const int qb = blockIdx.y;

    const bf16* Qb = Q + (size_t)(b * 512 + qb * 64) * 1024 + h * 64;
    const bf16* Kb = Kg + (size_t)(b * 512) * ldK + h * 64;
    const bf16* Vb = Vt + (size_t)b * 262144 + (size_t)(h * 64) * 512;

    bf16x8_t qf[2];
    {
        const bf16* qr = Qb + (size_t)(w * 16 + (lane & 15)) * 1024 + (lane >> 4) * 8;
        qf[0] = *(const bf16x8_t*)qr;
        qf[1] = *(const bf16x8_t*)(qr + 32);
    }

    f32x4_t oacc[4] = {};
    float mrow[4] = {-1e30f, -1e30f, -1e30f, -1e30f};
    float lrow[4] = {0.f, 0.f, 0.f, 0.f};

    for (int kt = 0; kt < 4; ++kt) {
#pragma unroll
        for (int rd = 0; rd < 4; ++rd) {
            const int id = t + rd * 256;
            const int kr = id >> 3, sl = id & 7;
            gload16(Kb + (size_t)(kt * 128 + kr) * ldK + ((sl ^ (kr & 7)) * 8),
                    &klds[id * 8]);
        }
#pragma unroll
        for (int rd = 0; rd < 4; ++rd) {
            const int id = t + rd * 256;
            const int dr = id >> 4, sl = id & 15;
            gload16(Vb + (size_t)dr * 512 + kt * 128 + ((sl ^ (dr & 7)) * 8),
                    &vlds[id * 8]);
        }
        __syncthreads();

        // QK^T
        f32x4_t sc[8] = {};
        __builtin_amdgcn_s_setprio(1);
#pragma unroll
        for (int kf = 0; kf < 8; ++kf) {
            const int krow = kf * 16 + (lane & 15);
#pragma unroll
            for (int ks = 0; ks < 2; ++ks) {
                const int slot = (ks * 4 + (lane >> 4)) ^ (krow & 7);
                bf16x8_t kfr = *(const bf16x8_t*)&klds[krow * 64 + slot * 8];
                sc[kf] = __builtin_amdgcn_mfma_f32_16x16x32_bf16(qf[ks], kfr, sc[kf], 0, 0, 0);
            }
        }
        __builtin_amdgcn_s_setprio(0);
        // online softmax
        float tm[4] = {-1e30f, -1e30f, -1e30f, -1e30f};
#pragma unroll
        for (int kf = 0; kf < 8; ++kf)
#pragma unroll
            for (int r = 0; r < 4; ++r) {
                sc[kf][r] *= qscale;
                tm[r] = fmaxf(tm[r], sc[kf][r]);
            }
#pragma unroll
        for (int mm = 1; mm < 16; mm <<= 1)
#pragma unroll
            for (int r = 0; r < 4; ++r) tm[r] = fmaxf(tm[r], __shfl_xor(tm[r], mm, 64));
        float mnew[4], scal[4], ts[4] = {0.f, 0.f, 0.f, 0.f};
#pragma unroll
        for (int r = 0; r < 4; ++r) {
            mnew[r] = fmaxf(mrow[r], tm[r]);
            scal[r] = __expf(mrow[r] - mnew[r]);
            mrow[r] = mnew[r];
        }
#pragma unroll
        for (int kf = 0; kf < 8; ++kf)
#pragma unroll
            for (int r = 0; r < 4; ++r) {
                const float p = __expf(sc[kf][r] - mnew[r]);
                ts[r] += p;
                plds[w][((lane >> 4) * 4 + r) * 136 + kf * 16 + (lane & 15)] = f2bf_bits(p);
            }
#pragma unroll
        for (int mm = 1; mm < 16; mm <<= 1)
#pragma unroll
            for (int r = 0; r < 4; ++r) ts[r] += __shfl_xor(ts[r], mm, 64);
#pragma unroll
        for (int r = 0; r < 4; ++r) lrow[r] = lrow[r] * scal[r] + ts[r];
#pragma unroll
        for (int n = 0; n < 4; ++n)
#pragma unroll
            for (int r = 0; r < 4; ++r) oacc[n][r] *= scal[r];
        // PV
        __builtin_amdgcn_s_setprio(1);
#pragma unroll
        for (int ks2 = 0; ks2 < 4; ++ks2) {
            bf16x8_t pa =
                *(const bf16x8_t*)&plds[w][(lane & 15) * 136 + ks2 * 32 + (lane >> 4) * 8];
#pragma unroll
            for (int n = 0; n < 4; ++n) {
                const int drow = n * 16 + (lane & 15);
                const int slot = (ks2 * 4 + (lane >> 4)) ^ (drow & 7);
                bf16x8_t vbf = *(const bf16x8_t*)&vlds[drow * 128 + slot * 8];
                oacc[n] = __builtin_amdgcn_mfma_f32_16x16x32_bf16(pa, vbf, oacc[n], 0, 0, 0);
            }
        }
        __builtin_amdgcn_s_setprio(0);
        __syncthreads();
    }
    // epilogue: out = oacc / l, via plds for coalesced 16B stores
#pragma unroll
    for (int r = 0; r < 4; ++r) {
        const float inv = 1.0f / lrow[r];
#pragma unroll
        for (int n = 0; n < 4; ++n)
            plds[w][((lane >> 4) * 4 + r) * 136 + n * 16 + (lane & 15)] =
                f2bf_bits(oacc[n][r] * inv);
    }
    __syncthreads();
    {
        bf16* Ob = O + (size_t)(b * 512 + qb * 64 + w * 16) * ldO + h * 64;
#pragma unroll
        for (int it = 0; it < 2; ++it) {
            const int seg = lane + it * 64;
            const int row = seg >> 3, c8 = (seg & 7) * 8;
            u16x8 val = *(const u16x8*)&plds[w][row * 136 + c8];
            *(u16x8*)&Ob[(size_t)row * ldO + c8] = val;
        }
    }
}

// ---------------------------------------------------------------------------
// out = LN(x + a) * alpha + beta (unbiased std, no eps). One wave per row.
// x, a bf16; output bf16 (ob) and/or fp32 (of).
// ---------------------------------------------------------------------------
__global__ __launch_bounds__(256) void add_ln_kernel(
    const bf16* __restrict__ a, const bf16* __restrict__ x,
    const float* __restrict__ alpha, const float* __restrict__ beta,
    float* __restrict__ of, bf16* __restrict__ ob) {
    const int row = blockIdx.x * 4 + (threadIdx.x >> 6);
    const int lane = threadIdx.x & 63;
    const size_t base = (size_t)row * 512 + lane * 8;
    float v[8];
    {
        u16x8 ux = *(const u16x8*)(x + base);
#pragma unroll
        for (int j = 0; j < 8; ++j) v[j] = bfbits2f(ux[j]);
    }
    if (a) {
        u16x8 ua = *(const u16x8*)(a + base);
#pragma unroll
        for (int j = 0; j < 8; ++j) v[j] += bfbits2f(ua[j]);
    }
    float s = 0.f, ss = 0.f;
#pragma unroll
    for (int j = 0; j < 8; ++j) { s += v[j]; ss += v[j] * v[j]; }
#pragma unroll
    for (int m = 1; m < 64; m <<= 1) {
        s += __shfl_xor(s, m, 64);
        ss += __shfl_xor(ss, m, 64);
    }
    const float mean = s * (1.0f / 512.0f);
    const float var = (ss - s * mean) * (1.0f / 511.0f);
    const float rstd = rsqrtf(var);
    const int col = lane * 8;
    const float4* alp = (const float4*)(alpha + col);
    const float4* bep = (const float4*)(beta + col);
    float4 al0 = alp[0], al1 = alp[1], be0 = bep[0], be1 = bep[1];
    float al[8] = {al0.x, al0.y, al0.z, al0.w, al1.x, al1.y, al1.z, al1.w};
    float be[8] = {be0.x, be0.y, be0.z, be0.w, be1.x, be1.y, be1.z, be1.w};
    float y[8];
#pragma unroll
    for (int j = 0; j < 8; ++j) y[j] = (v[j] - mean) * rstd * al[j] + be[j];
    if (ob) {
        u16x8 u;
#pragma unroll
        for (int j = 0; j < 8; ++j) u[j] = f2bf_bits(y[j]);
        *(u16x8*)(ob + base) = u;
    }
    if (of) {
        float4 o0, o1;
        o0.x = y[0]; o0.y = y[1]; o0.z = y[2]; o0.w = y[3];
        o1.x = y[4]; o1.y = y[5]; o1.z = y[6]; o1.w = y[7];
        float4* op = (float4*)(of + base);
        op[0] = o0; op[1] = o1;
    }
}

// ---------------------------------------------------------------------------
extern "C" void kernel_launch(void* const* d_in, const int* in_sizes, int n_in,
                              void* d_out, int out_size, void* d_ws, size_t ws_size,
                              hipStream_t stream) {
    (void)in_sizes; (void)n_in; (void)out_size;

    const float* in_enc = (const float*)d_in[0];
    const float* in_dec = (const float*)d_in[1];
    const float* enc_W  = (const float*)d_in[2];
    const float* enc_b  = (const float*)d_in[3];
    const float* enc_W1 = (const float*)d_in[4];
    const float* enc_b1 = (const float*)d_in[5];
    const float* enc_W2 = (const float*)d_in[6];
    const float* enc_b2 = (const float*)d_in[7];
    const float* enc_al = (const float*)d_in[8];
    const float* enc_be = (const float*)d_in[9];
    const float* dec_W  = (const float*)d_in[10];
    const float* dec_b  = (const float*)d_in[11];
    const float* dec_W1 = (const float*)d_in[12];
    const float* dec_b1 = (const float*)d_in[13];
    const float* dec_W2 = (const float*)d_in[14];
    const float* dec_b2 = (const float*)d_in[15];
    const float* dec_al = (const float*)d_in[16];
    const float* dec_be = (const float*)d_in[17];
    const float* fin_al = (const float*)d_in[18];
    const float* fin_be = (const float*)d_in[19];

    constexpr int Dm = 512, FFm = 2048, Lm = 6;
    constexpr int M = 4096;  // B*S
    const size_t DD = (size_t)Dm * Dm;
    const size_t DFF = (size_t)Dm * FFm;
    const long long MD = (long long)M * Dm;  // 2097152
    const float QSCALE = 0.04419417382415922f;  // 1/sqrt(512)

    char* wsp = (char*)d_ws;
    auto alloc = [&](size_t bytes) -> char* {
        char* p = wsp;
        wsp += (bytes + 255) & ~(size_t)255;
        return p;
    };

    bf16* wtEncW  = (bf16*)alloc(sizeof(bf16) * 24 * DD);
    bf16* wtEncW1 = (bf16*)alloc(sizeof(bf16) * 6 * DFF);
    bf16* wtEncW2 = (bf16*)alloc(sizeof(bf16) * 6 * DFF);
    bf16* wtDecW  = (bf16*)alloc(sizeof(bf16) * 48 * DD);
    bf16* wtDecW1 = (bf16*)alloc(sizeof(bf16) * 6 * DFF);
    bf16* wtDecW2 = (bf16*)alloc(sizeof(bf16) * 6 * DFF);
    bf16* qkvbuf = (bf16*)alloc(sizeof(bf16) * M * 1024);  // Q cols 0..511; K / attn-out cols 512..1023
    bf16* vt     = (bf16*)alloc(sizeof(bf16) * M * Dm);    // self V^T [b][d][k]
    bf16* ckbuf  = (bf16*)alloc(sizeof(bf16) * M * Dm);    // self-attn out
    bf16* ck6    = (bf16*)alloc(sizeof(bf16) * 6 * M * Dm);  // cross K, all layers
    bf16* cv6    = (bf16*)alloc(sizeof(bf16) * 6 * M * Dm);  // cross V^T, all layers
    bf16* ffnmid = (bf16*)alloc(sizeof(bf16) * M * FFm);
    bf16* projb  = (bf16*)alloc(sizeof(bf16) * M * Dm);    // residual branch
    bf16* zAb = (bf16*)alloc(sizeof(bf16) * M * Dm);
    bf16* zBb = (bf16*)alloc(sizeof(bf16) * M * Dm);
    bf16* zCb = (bf16*)alloc(sizeof(bf16) * M * Dm);       // decoder input (pre-cast)
    bf16* zencb = (bf16*)alloc(sizeof(bf16) * M * Dm);

    if ((size_t)(wsp - (char*)d_ws) > ws_size) return;

    // ---- one-time prep: weight transpose (batched) + input casts ----
    {
        dim3 bl(32, 8);
        wtrans2_kernel<<<dim3(Dm / 32, Dm / 32, 72), bl, 0, stream>>>(
            enc_W, wtEncW, 24, dec_W, wtDecW, Dm, Dm);
        wtrans2_kernel<<<dim3(FFm / 32, Dm / 32, 12), bl, 0, stream>>>(
            enc_W1, wtEncW1, 6, dec_W1, wtDecW1, Dm, FFm);
        wtrans2_kernel<<<dim3(Dm / 32, FFm / 32, 12), bl, 0, stream>>>(
            enc_W2, wtEncW2, 6, dec_W2, wtDecW2, FFm, Dm);
        cast_kernel<<<2048, 256, 0, stream>>>(in_enc, zAb);
        cast_kernel<<<2048, 256, 0, stream>>>(in_dec, zCb);
    }

    bf16* curB = zAb;
    bf16* othB = zBb;
    auto swapbuf = [&]() { bf16* tb = curB; curB = othB; othB = tb; };

    // self-attention: fused QKV proj (V -> vt transposed), flash, outproj
    auto self_attention = [&](const bf16* src, const bf16* Wt4, const float* b4) {
        gemm_nt<128, 128, EPI_QKV, true, 512, 2, 4><<<dim3(32, 12, 1), 512, 0, stream>>>(
            src, Wt4, b4, qkvbuf, vt, Dm, Dm, Dm, 1024, 1024, 0, 0, 0, 0);
        flash_kernel<<<dim3(64, 8), 256, 0, stream>>>(
            qkvbuf, qkvbuf + 512, vt, ckbuf, 1024, 512, QSCALE);
        gemm_nt<64, 64, EPI_BF16, true, 256, 2, 2><<<dim3(64, 8, 1), 256, 0, stream>>>(
            ckbuf, Wt4 + 3 * DD, b4 + 3 * Dm, projb, nullptr, Dm, 512, Dm, Dm, 0,
            0, 0, 0, 0);
    };

    // cross-attention layer i: Q proj, flash vs precomputed ck6/cv6, outproj
    auto cross_attention = [&](const bf16* src, const bf16* Wt4, const float* b4, int i) {
        gemm_nt<64, 64, EPI_BF16, true, 256, 2, 2><<<dim3(64, 8, 1), 256, 0, stream>>>(
            src, Wt4, b4, qkvbuf, nullptr, Dm, Dm, Dm, 1024, 0, 0, 0, 0, 0);
        flash_kernel<<<dim3(64, 8), 256, 0, stream>>>(
            qkvbuf, ck6 + (long long)i * MD, cv6 + (long long)i * MD, qkvbuf + 512,
            512, 1024, QSCALE);
        gemm_nt<64, 64, EPI_BF16, true, 256, 2, 2><<<dim3(64, 8, 1), 256, 0, stream>>>(
            qkvbuf + 512, Wt4 + 3 * DD, b4 + 3 * Dm, projb, nullptr, Dm, 1024, Dm, Dm, 0,
            0, 0, 0, 0);
    };

    auto ffn = [&](const bf16* src, const bf16* W1t, const float* b1v,
                   const bf16* W2t, const float* b2v) {
        gemm_nt<128, 128, EPI_RELU, true, 512, 2, 4><<<dim3(32, 16, 1), 512, 0, stream>>>(
            src, W1t, b1v, ffnmid, nullptr, Dm, Dm, Dm, FFm, 0, 0, 0, 0, 0);
        gemm_nt<64, 64, EPI_BF16, true, 256, 2, 2><<<dim3(64, 8, 1), 256, 0, stream>>>(
            ffnmid, W2t, b2v, projb, nullptr, FFm, FFm, FFm, Dm, 0, 0, 0, 0, 0);
    };

    // ================= encoder =================
    for (int i = 0; i < Lm; ++i) {
        self_attention(curB, wtEncW + (size_t)i * 4 * DD, enc_b + (size_t)i * 4 * Dm);
        add_ln_kernel<<<1024, 256, 0, stream>>>(
            projb, curB, enc_al + (size_t)(i * 2) * Dm, enc_be + (size_t)(i * 2) * Dm,
            nullptr, othB);
        swapbuf();
        ffn(curB, wtEncW1 + (size_t)i * DFF, enc_b1 + (size_t)i * FFm,
            wtEncW2 + (size_t)i * DFF, enc_b2 + (size_t)i * Dm);
        add_ln_kernel<<<1024, 256, 0, stream>>>(
            projb, curB, enc_al + (size_t)(i * 2 + 1) * Dm, enc_be + (size_t)(i * 2 + 1) * Dm,
            nullptr, othB);
        swapbuf();
    }
    add_ln_kernel<<<1024, 256, 0, stream>>>(nullptr, curB, fin_al, fin_be, nullptr, zencb);

    // Precompute cross K/V for ALL 6 decoder layers in one batched GEMM.
    gemm_nt<128, 128, EPI_QKV, true, 512, 2, 4><<<dim3(32, 8, 6), 512, 0, stream>>>(
        zencb, wtDecW + 5 * DD, dec_b + 5 * Dm, ck6, cv6, Dm, Dm, Dm, 512, 512,
        /*oBz=*/8LL * (long long)DD, /*oCz=*/MD, /*oCvz=*/MD, /*oBiasz=*/8LL * Dm);

    // ================= decoder =================
    curB = zCb; othB = zBb;
    for (int i = 0; i < Lm; ++i) {
        self_attention(curB, wtDecW + (size_t)(i * 2 + 0) * 4 * DD,
                       dec_b + (size_t)(i * 2 + 0) * 4 * Dm);
        add_ln_kernel<<<1024, 256, 0, stream>>>(
            projb, curB, dec_al + (size_t)(i * 3 + 0) * Dm, dec_be + (size_t)(i * 3 + 0) * Dm,
            nullptr, othB);
        if (curB == zCb) { curB = othB; othB = zAb; }
        else swapbuf();
        cross_attention(curB, wtDecW + (size_t)(i * 2 + 1) * 4 * DD,
                        dec_b + (size_t)(i * 2 + 1) * 4 * Dm, i);
        add_ln_kernel<<<1024, 256, 0, stream>>>(
            projb, curB, dec_al + (size_t)(i * 3 + 1) * Dm, dec_be + (size_t)(i * 3 + 1) * Dm,
            nullptr, othB);
        swapbuf();
        ffn(curB, wtDecW1 + (size_t)i * DFF, dec_b1 + (size_t)i * FFm,
            wtDecW2 + (size_t)i * DFF, dec_b2 + (size_t)i * Dm);
        add_ln_kernel<<<1024, 256, 0, stream>>>(
            projb, curB, dec_al + (size_t)(i * 3 + 2) * Dm, dec_be + (size_t)(i * 3 + 2) * Dm,
            nullptr, othB);
        swapbuf();
    }
    add_ln_kernel<<<1024, 256, 0, stream>>>(nullptr, curB, fin_al + Dm, fin_be + Dm,
                                            (float*)d_out, nullptr);
}

// Round 13
// 1171.237 us; speedup vs baseline: 1.0744x; 1.0675x over previous
//
#include <hip/hip_runtime.h>
#include <hip/hip_bf16.h>
#include <cstdint>

using bf16 = __hip_bfloat16;

typedef __bf16 bf16x8_t __attribute__((ext_vector_type(8)));
typedef float f32x4_t __attribute__((ext_vector_type(4)));
typedef unsigned short u16x8 __attribute__((ext_vector_type(8)));

enum { EPI_BF16 = 0, EPI_QKV = 2, EPI_RELU = 4 };

__device__ __forceinline__ unsigned short f2bf_bits(float f) {
    bf16 h = __float2bfloat16(f);
    return *reinterpret_cast<unsigned short*>(&h);
}
__device__ __forceinline__ float bfbits2f(unsigned short u) {
    return __uint_as_float(((unsigned)u) << 16);
}
__device__ __forceinline__ void gload16(const void* g, void* l) {
    __builtin_amdgcn_global_load_lds(
        (const __attribute__((address_space(1))) void*)g,
        (__attribute__((address_space(3))) void*)l, 16, 0, 0);
}
// raw barrier with compiler memory fences (no vmcnt drain, unlike __syncthreads)
__device__ __forceinline__ void raw_barrier() {
    asm volatile("" ::: "memory");
    __builtin_amdgcn_s_barrier();
    asm volatile("" ::: "memory");
}

// ---------------------------------------------------------------------------
// Batched weight transpose + fp32->bf16 for TWO tensors (z-switch):
// z < nz0 -> W0 slice z; else W1 slice z-nz0.  W[b][K][N] -> Wt[b][N][K]
// ---------------------------------------------------------------------------
__global__ __launch_bounds__(256) void wtrans2_kernel(
    const float* __restrict__ W0, bf16* __restrict__ T0, int nz0,
    const float* __restrict__ W1, bf16* __restrict__ T1, int Kd, int Nd) {
    __shared__ float tile[32][33];
    int b = blockIdx.z;
    const float* Wb;
    bf16* Tb;
    if (b < nz0) {
        Wb = W0 + (size_t)b * Kd * Nd;
        Tb = T0 + (size_t)b * Kd * Nd;
    } else {
        Wb = W1 + (size_t)(b - nz0) * Kd * Nd;
        Tb = T1 + (size_t)(b - nz0) * Kd * Nd;
    }
    const int n0 = blockIdx.x * 32, k0 = blockIdx.y * 32;
    const int tx = threadIdx.x, ty = threadIdx.y;
#pragma unroll
    for (int i = 0; i < 32; i += 8)
        tile[ty + i][tx] = Wb[(size_t)(k0 + ty + i) * Nd + n0 + tx];
    __syncthreads();
#pragma unroll
    for (int i = 0; i < 32; i += 8)
        Tb[(size_t)(n0 + ty + i) * Kd + k0 + tx] = __float2bfloat16(tile[tx][ty + i]);
}

// ---------------------------------------------------------------------------
// fp32 -> bf16 cast, 4 elems/thread
// ---------------------------------------------------------------------------
__global__ __launch_bounds__(256) void cast_kernel(
    const float* __restrict__ x, bf16* __restrict__ ob) {
    const int i = blockIdx.x * 256 + threadIdx.x;
    float4 v = ((const float4*)x)[i];
    uint2 pk;
    pk.x = ((unsigned)f2bf_bits(v.y) << 16) | f2bf_bits(v.x);
    pk.y = ((unsigned)f2bf_bits(v.w) << 16) | f2bf_bits(v.z);
    ((uint2*)ob)[i] = pk;
}

// ---------------------------------------------------------------------------
// NT GEMM:  C[M,N] = A[M,K] * Bt[N,K]^T (+bias) with epilogues.
// bf16 in, fp32 MFMA accum. NT threads = NT/64 waves in WM x WN grid. BK=64.
// 2-phase double-buffered K-loop with T4 COUNTED VMCNT (m218/HK):
//   STAGE(next) -> s_waitcnt vmcnt(LPB) [cur landed, next in flight]
//   -> raw s_barrier -> COMPUTE(cur) -> raw s_barrier (read-complete).
// The next-buffer loads stay in flight ACROSS both barriers (no vmcnt(0)
// drain - that drain was ~72% of the K-step critical path, m233).
// LPB = BM/RR + BN/RR = 4 loads/thread/buffer for all configs used here.
// T2 swizzle via rule-21. Epilogue via swizzled LDS tile -> coalesced 16B.
// blockIdx.z batches over weights/outputs via oBz/oCz/oCvz/oBiasz.
// ---------------------------------------------------------------------------
template <int BM, int BN, int EPI, bool HASBIAS, int NT = 256, int WM = 2, int WN = 2>
__global__ __launch_bounds__(NT) void gemm_nt(
    const bf16* __restrict__ A, const bf16* __restrict__ B,
    const float* __restrict__ bias, void* __restrict__ Cout, void* __restrict__ Caux,
    int K, int ldA, int ldB, int ldC, int vcol0,
    long long oBz, long long oCz, long long oCvz, long long oBiasz) {
    static_assert(BM % 32 == 0 && BN % 32 == 0, "tile");
    static_assert(WM * WN == NT / 64, "wave grid");
    constexpr int RR = NT / 8;
    static_assert(BM % RR == 0 && BN % RR == 0, "staging");
    constexpr int LPB = BM / RR + BN / RR;    // loads per thread per buffer
    static_assert(LPB == 4, "vmcnt constant assumes 4 loads/buffer");
    constexpr int WTM = (BM / WM) / 16;
    constexpr int WTN = (BN / WN) / 16;
    constexpr int STG = 2 * (BM + BN) * 64;   // double-buffered staging elems
    constexpr int CTE = BM * BN;              // epilogue tile elems
    __shared__ alignas(16) bf16 smem[STG > CTE ? STG : CTE];
    bf16* lsA0 = smem;
    bf16* lsB0 = smem + BM * 64;
    bf16* lsA1 = smem + (BM + BN) * 64;
    bf16* lsB1 = lsA1 + BM * 64;

    const int t = threadIdx.x;
    const int lane = t & 63;
    const int wave = t >> 6;
    const int wm = wave / WN, wn = wave % WN;
    const int z = blockIdx.z;

    const int brow = blockIdx.x * BM, bcol = blockIdx.y * BN;
    const bf16* Ab = A + (size_t)brow * ldA;
    const bf16* Bb = B + (long long)z * oBz + (size_t)bcol * ldB;
    const float* biasz = HASBIAS ? bias + (long long)z * oBiasz : bias;

    const int srow = t >> 3;
    const int sdst = (t & 7) * 8;                 // linear LDS slot
    const int ssrc = ((t & 7) ^ (srow & 7)) * 8;  // swizzled global slot

    f32x4_t acc[WTM][WTN] = {};

#define GEMM_STAGE(AA, BB, kt)                                                \
    {                                                                         \
        _Pragma("unroll")                                                     \
        for (int r = 0; r < BM / RR; ++r)                                     \
            gload16(Ab + (size_t)(srow + r * RR) * ldA + (kt) + ssrc,         \
                    &AA[(srow + r * RR) * 64 + sdst]);                        \
        _Pragma("unroll")                                                     \
        for (int r = 0; r < BN / RR; ++r)                                     \
            gload16(Bb + (size_t)(srow + r * RR) * ldB + (kt) + ssrc,         \
                    &BB[(srow + r * RR) * 64 + sdst]);                        \
    }

#define GEMM_COMPUTE(AA, BB)                                                  \
    {                                                                         \
        _Pragma("unroll")                                                     \
        for (int ks = 0; ks < 2; ++ks) {                                      \
            bf16x8_t af[WTM], bfr[WTN];                                       \
            _Pragma("unroll")                                                 \
            for (int m = 0; m < WTM; ++m) {                                   \
                const int rowA = wm * (BM / WM) + m * 16 + (lane & 15);       \
                const int slot = ks * 4 + (lane >> 4);                        \
                af[m] = *(const bf16x8_t*)&AA[rowA * 64 + ((slot ^ (rowA & 7)) * 8)]; \
            }                                                                 \
            _Pragma("unroll")                                                 \
            for (int n = 0; n < WTN; ++n) {                                   \
                const int rowB = wn * (BN / WN) + n * 16 + (lane & 15);       \
                const int slot = ks * 4 + (lane >> 4);                        \
                bfr[n] = *(const bf16x8_t*)&BB[rowB * 64 + ((slot ^ (rowB & 7)) * 8)]; \
            }                                                                 \
            _Pragma("unroll")                                                 \
            for (int m = 0; m < WTM; ++m)                                     \
                _Pragma("unroll")                                             \
                for (int n = 0; n < WTN; ++n)                                 \
                    acc[m][n] = __builtin_amdgcn_mfma_f32_16x16x32_bf16(      \
                        af[m], bfr[n], acc[m][n], 0, 0, 0);                   \
        }                                                                     \
    }

// wait for current buffer (leave HAVE_NEXT ? LPB : 0 loads in flight)
#define GEMM_WAIT(HAVE_NEXT)                                                  \
    {                                                                         \
        if (HAVE_NEXT) asm volatile("s_waitcnt vmcnt(4)" ::: "memory");       \
        else           asm volatile("s_waitcnt vmcnt(0)" ::: "memory");       \
        __builtin_amdgcn_sched_barrier(0);                                    \
        raw_barrier();                                                        \
    }

    GEMM_STAGE(lsA0, lsB0, 0);
    int kt = 0;
    while (true) {
        int kn = kt + 64;
        const bool havenext = (kn < K);
        if (havenext) GEMM_STAGE(lsA1, lsB1, kn);   // prefetch stays in flight
        GEMM_WAIT(havenext);                        // cur ready; no full drain
        GEMM_COMPUTE(lsA0, lsB0);
        raw_barrier();                              // readers done before overwrite
        kt = kn;
        if (kt >= K) break;
        kn = kt + 64;
        const bool havenext2 = (kn < K);
        if (havenext2) GEMM_STAGE(lsA0, lsB0, kn);
        GEMM_WAIT(havenext2);
        GEMM_COMPUTE(lsA1, lsB1);
        raw_barrier();
        kt = kn;
        if (kt >= K) break;
    }
#undef GEMM_STAGE
#undef GEMM_COMPUTE
#undef GEMM_WAIT

    // ---- epilogue: frags -> swizzled LDS tile -> coalesced stores ----
    // C/D layout: col = lane&15, row = (lane>>4)*4 + reg  [m89/m91]
    const int lr = (lane >> 4) * 4, lc = lane & 15;
    const bool isV = (EPI == EPI_QKV) && (bcol >= vcol0);  // uniform per block
    unsigned short* cts = (unsigned short*)smem;
#pragma unroll
    for (int m = 0; m < WTM; ++m) {
        const int row0 = wm * (BM / WM) + m * 16 + lr;   // local row base
#pragma unroll
        for (int n = 0; n < WTN; ++n) {
            const int col = wn * (BN / WN) + n * 16 + lc;  // local col
            float bv = 0.f;
            if constexpr (HASBIAS) bv = biasz[bcol + col];
            unsigned short h4[4];
#pragma unroll
            for (int r = 0; r < 4; ++r) {
                float x = acc[m][n][r] + bv;
                if constexpr (EPI == EPI_RELU) x = fmaxf(x, 0.f);
                h4[r] = f2bf_bits(x);
            }
            if (isV) {
                // transposed tile: ctV[col][q], q-run of 4 contiguous (8B)
                union { unsigned short h[4]; uint2 u; } pk;
#pragma unroll
                for (int r = 0; r < 4; ++r) pk.h[r] = h4[r];
                *(uint2*)&cts[col * BM + (row0 ^ ((col & 7) << 3))] = pk.u;
            } else {
#pragma unroll
                for (int r = 0; r < 4; ++r)
                    cts[(row0 + r) * BN + (col ^ (((row0 + r) & 7) << 3))] = h4[r];
            }
        }
    }
    __syncthreads();
    if (isV) {
        bf16* Cv = (bf16*)Caux + (long long)z * oCvz;
        const int bb = brow >> 9, qb0 = brow & 511;
        for (int s = t; s < CTE / 8; s += NT) {
            const int d = s / (BM / 8), q8 = (s % (BM / 8)) * 8;
            u16x8 val = *(const u16x8*)&cts[d * BM + (q8 ^ ((d & 7) << 3))];
            *(u16x8*)&Cv[(size_t)bb * 262144 + (size_t)(bcol - vcol0 + d) * 512 + qb0 + q8] = val;
        }
    } else {
        bf16* C = (bf16*)Cout + (long long)z * oCz;
        for (int s = t; s < CTE / 8; s += NT) {
            const int row = s / (BN / 8), c8 = (s % (BN / 8)) * 8;
            u16x8 val = *(const u16x8*)&cts[row * BN + (c8 ^ ((row & 7) << 3))];
            *(u16x8*)&C[(size_t)(brow + row) * ldC + bcol + c8] = val;
        }
    }
}

// ---------------------------------------------------------------------------
// Flash attention: one block per (b*8+h, qblk). 256 threads (4 waves),
// QBLK=64 (16 q-rows/wave), KT=128 x 4 tiles, online softmax.
// Grid (64, 8): q-blocks sharing K/V have id-stride 64 == 0 mod 8 (co-XCD).
// T5 setprio around MFMA clusters (independent blocks at different phases).
// Coalesced 16B output via plds round-trip.
// ---------------------------------------------------------------------------
__global__ __launch_bounds__(256) void flash_kernel(
    const bf16* __restrict__ Q, const bf16* __restrict__ Kg,
    const bf16* __restrict__ Vt, bf16* __restrict__ O,
    int ldK, int ldO, float qscale) {
    __shared__ alignas(16) bf16 klds[128 * 64];
    __shared__ alignas(16) bf16 vlds[64 * 128];
    __shared__ alignas(16) unsigned short plds[4][16 * 136];

    const int t = threadIdx.x, lane = t & 63, w = t >> 6;
    const int bh = blockIdx.x;
    const int b = bh >> 3, h = bh & 7;
    const int qb = blockIdx.y;

    const bf16* Qb = Q + (size_t)(b * 512 + qb * 64) * 1024 + h * 64;
    const bf16* Kb = Kg + (size_t)(b * 512) * ldK + h * 64;
    const bf16* Vb = Vt + (size_t)b * 262144 + (size_t)(h * 64) * 512;

    bf16x8_t qf[2];
    {
        const bf16* qr = Qb + (size_t)(w * 16 + (lane & 15)) * 1024 + (lane >> 4) * 8;
        qf[0] = *(const bf16x8_t*)qr;
        qf[1] = *(const bf16x8_t*)(qr + 32);
    }

    f32x4_t oacc[4] = {};
    float mrow[4] = {-1e30f, -1e30f, -1e30f, -1e30f};
    float lrow[4] = {0.f, 0.f, 0.f, 0.f};

    for (int kt = 0; kt < 4; ++kt) {
#pragma unroll
        for (int rd = 0; rd < 4; ++rd) {
            const int id = t + rd * 256;
            const int kr = id >> 3, sl = id & 7;
            gload16(Kb + (size_t)(kt * 128 + kr) * ldK + ((sl ^ (kr & 7)) * 8),
                    &klds[id * 8]);
        }
#pragma unroll
        for (int rd = 0; rd < 4; ++rd) {
            const int id = t + rd * 256;
            const int dr = id >> 4, sl = id & 15;
            gload16(Vb + (size_t)dr * 512 + kt * 128 + ((sl ^ (dr & 7)) * 8),
                    &vlds[id * 8]);
        }
        __syncthreads();

        // QK^T
        f32x4_t sc[8] = {};
        __builtin_amdgcn_s_setprio(1);
#pragma unroll
        for (int kf = 0; kf < 8; ++kf) {
            const int krow = kf * 16 + (lane & 15);
#pragma unroll
            for (int ks = 0; ks < 2; ++ks) {
                const int slot = (ks * 4 + (lane >> 4)) ^ (krow & 7);
                bf16x8_t kfr = *(const bf16x8_t*)&klds[krow * 64 + slot * 8];
                sc[kf] = __builtin_amdgcn_mfma_f32_16x16x32_bf16(qf[ks], kfr, sc[kf], 0, 0, 0);
            }
        }
        __builtin_amdgcn_s_setprio(0);
        // online softmax
        float tm[4] = {-1e30f, -1e30f, -1e30f, -1e30f};
#pragma unroll
        for (int kf = 0; kf < 8; ++kf)
#pragma unroll
            for (int r = 0; r < 4; ++r) {
                sc[kf][r] *= qscale;
                tm[r] = fmaxf(tm[r], sc[kf][r]);
            }
#pragma unroll
        for (int mm = 1; mm < 16; mm <<= 1)
#pragma unroll
            for (int r = 0; r < 4; ++r) tm[r] = fmaxf(tm[r], __shfl_xor(tm[r], mm, 64));
        float mnew[4], scal[4], ts[4] = {0.f, 0.f, 0.f, 0.f};
#pragma unroll
        for (int r = 0; r < 4; ++r) {
            mnew[r] = fmaxf(mrow[r], tm[r]);
            scal[r] = __expf(mrow[r] - mnew[r]);
            mrow[r] = mnew[r];
        }
#pragma unroll
        for (int kf = 0; kf < 8; ++kf)
#pragma unroll
            for (int r = 0; r < 4; ++r) {
                const float p = __expf(sc[kf][r] - mnew[r]);
                ts[r] += p;
                plds[w][((lane >> 4) * 4 + r) * 136 + kf * 16 + (lane & 15)] = f2bf_bits(p);
            }
#pragma unroll
        for (int mm = 1; mm < 16; mm <<= 1)
#pragma unroll
            for (int r = 0; r < 4; ++r) ts[r] += __shfl_xor(ts[r], mm, 64);
#pragma unroll
        for (int r = 0; r < 4; ++r) lrow[r] = lrow[r] * scal[r] + ts[r];
#pragma unroll
        for (int n = 0; n < 4; ++n)
#pragma unroll
            for (int r = 0; r < 4; ++r) oacc[n][r] *= scal[r];
        // PV
        __builtin_amdgcn_s_setprio(1);
#pragma unroll
        for (int ks2 = 0; ks2 < 4; ++ks2) {
            bf16x8_t pa =
                *(const bf16x8_t*)&plds[w][(lane & 15) * 136 + ks2 * 32 + (lane >> 4) * 8];
#pragma unroll
            for (int n = 0; n < 4; ++n) {
                const int drow = n * 16 + (lane & 15);
                const int slot = (ks2 * 4 + (lane >> 4)) ^ (drow & 7);
                bf16x8_t vbf = *(const bf16x8_t*)&vlds[drow * 128 + slot * 8];
                oacc[n] = __builtin_amdgcn_mfma_f32_16x16x32_bf16(pa, vbf, oacc[n], 0, 0, 0);
            }
        }
        __builtin_amdgcn_s_setprio(0);
        __syncthreads();
    }
    // epilogue: out = oacc / l, via plds for coalesced 16B stores
#pragma unroll
    for (int r = 0; r < 4; ++r) {
        const float inv = 1.0f / lrow[r];
#pragma unroll
        for (int n = 0; n < 4; ++n)
            plds[w][((lane >> 4) * 4 + r) * 136 + n * 16 + (lane & 15)] =
                f2bf_bits(oacc[n][r] * inv);
    }
    __syncthreads();
    {
        bf16* Ob = O + (size_t)(b * 512 + qb * 64 + w * 16) * ldO + h * 64;
#pragma unroll
        for (int it = 0; it < 2; ++it) {
            const int seg = lane + it * 64;
            const int row = seg >> 3, c8 = (seg & 7) * 8;
            u16x8 val = *(const u16x8*)&plds[w][row * 136 + c8];
            *(u16x8*)&Ob[(size_t)row * ldO + c8] = val;
        }
    }
}

// ---------------------------------------------------------------------------
// out = LN(x + a) * alpha + beta (unbiased std, no eps). One wave per row.
// x, a bf16; output bf16 (ob) and/or fp32 (of).
// ---------------------------------------------------------------------------
__global__ __launch_bounds__(256) void add_ln_kernel(
    const bf16* __restrict__ a, const bf16* __restrict__ x,
    const float* __restrict__ alpha, const float* __restrict__ beta,
    float* __restrict__ of, bf16* __restrict__ ob) {
    const int row = blockIdx.x * 4 + (threadIdx.x >> 6);
    const int lane = threadIdx.x & 63;
    const size_t base = (size_t)row * 512 + lane * 8;
    float v[8];
    {
        u16x8 ux = *(const u16x8*)(x + base);
#pragma unroll
        for (int j = 0; j < 8; ++j) v[j] = bfbits2f(ux[j]);
    }
    if (a) {
        u16x8 ua = *(const u16x8*)(a + base);
#pragma unroll
        for (int j = 0; j < 8; ++j) v[j] += bfbits2f(ua[j]);
    }
    float s = 0.f, ss = 0.f;
#pragma unroll
    for (int j = 0; j < 8; ++j) { s += v[j]; ss += v[j] * v[j]; }
#pragma unroll
    for (int m = 1; m < 64; m <<= 1) {
        s += __shfl_xor(s, m, 64);
        ss += __shfl_xor(ss, m, 64);
    }
    const float mean = s * (1.0f / 512.0f);
    const float var = (ss - s * mean) * (1.0f / 511.0f);
    const float rstd = rsqrtf(var);
    const int col = lane * 8;
    const float4* alp = (const float4*)(alpha + col);
    const float4* bep = (const float4*)(beta + col);
    float4 al0 = alp[0], al1 = alp[1], be0 = bep[0], be1 = bep[1];
    float al[8] = {al0.x, al0.y, al0.z, al0.w, al1.x, al1.y, al1.z, al1.w};
    float be[8] = {be0.x, be0.y, be0.z, be0.w, be1.x, be1.y, be1.z, be1.w};
    float y[8];
#pragma unroll
    for (int j = 0; j < 8; ++j) y[j] = (v[j] - mean) * rstd * al[j] + be[j];
    if (ob) {
        u16x8 u;
#pragma unroll
        for (int j = 0; j < 8; ++j) u[j] = f2bf_bits(y[j]);
        *(u16x8*)(ob + base) = u;
    }
    if (of) {
        float4 o0, o1;
        o0.x = y[0]; o0.y = y[1]; o0.z = y[2]; o0.w = y[3];
        o1.x = y[4]; o1.y = y[5]; o1.z = y[6]; o1.w = y[7];
        float4* op = (float4*)(of + base);
        op[0] = o0; op[1] = o1;
    }
}

// ---------------------------------------------------------------------------
extern "C" void kernel_launch(void* const* d_in, const int* in_sizes, int n_in,
                              void* d_out, int out_size, void* d_ws, size_t ws_size,
                              hipStream_t stream) {
    (void)in_sizes; (void)n_in; (void)out_size;

    const float* in_enc = (const float*)d_in[0];
    const float* in_dec = (const float*)d_in[1];
    const float* enc_W  = (const float*)d_in[2];
    const float* enc_b  = (const float*)d_in[3];
    const float* enc_W1 = (const float*)d_in[4];
    const float* enc_b1 = (const float*)d_in[5];
    const float* enc_W2 = (const float*)d_in[6];
    const float* enc_b2 = (const float*)d_in[7];
    const float* enc_al = (const float*)d_in[8];
    const float* enc_be = (const float*)d_in[9];
    const float* dec_W  = (const float*)d_in[10];
    const float* dec_b  = (const float*)d_in[11];
    const float* dec_W1 = (const float*)d_in[12];
    const float* dec_b1 = (const float*)d_in[13];
    const float* dec_W2 = (const float*)d_in[14];
    const float* dec_b2 = (const float*)d_in[15];
    const float* dec_al = (const float*)d_in[16];
    const float* dec_be = (const float*)d_in[17];
    const float* fin_al = (const float*)d_in[18];
    const float* fin_be = (const float*)d_in[19];

    constexpr int Dm = 512, FFm = 2048, Lm = 6;
    constexpr int M = 4096;  // B*S
    const size_t DD = (size_t)Dm * Dm;
    const size_t DFF = (size_t)Dm * FFm;
    const long long MD = (long long)M * Dm;  // 2097152
    const float QSCALE = 0.04419417382415922f;  // 1/sqrt(512)

    char* wsp = (char*)d_ws;
    auto alloc = [&](size_t bytes) -> char* {
        char* p = wsp;
        wsp += (bytes + 255) & ~(size_t)255;
        return p;
    };

    bf16* wtEncW  = (bf16*)alloc(sizeof(bf16) * 24 * DD);
    bf16* wtEncW1 = (bf16*)alloc(sizeof(bf16) * 6 * DFF);
    bf16* wtEncW2 = (bf16*)alloc(sizeof(bf16) * 6 * DFF);
    bf16* wtDecW  = (bf16*)alloc(sizeof(bf16) * 48 * DD);
    bf16* wtDecW1 = (bf16*)alloc(sizeof(bf16) * 6 * DFF);
    bf16* wtDecW2 = (bf16*)alloc(sizeof(bf16) * 6 * DFF);
    bf16* qkvbuf = (bf16*)alloc(sizeof(bf16) * M * 1024);  // Q cols 0..511; K / attn-out cols 512..1023
    bf16* vt     = (bf16*)alloc(sizeof(bf16) * M * Dm);    // self V^T [b][d][k]
    bf16* ckbuf  = (bf16*)alloc(sizeof(bf16) * M * Dm);    // self-attn out
    bf16* ck6    = (bf16*)alloc(sizeof(bf16) * 6 * M * Dm);  // cross K, all layers
    bf16* cv6    = (bf16*)alloc(sizeof(bf16) * 6 * M * Dm);  // cross V^T, all layers
    bf16* ffnmid = (bf16*)alloc(sizeof(bf16) * M * FFm);
    bf16* projb  = (bf16*)alloc(sizeof(bf16) * M * Dm);    // residual branch
    bf16* zAb = (bf16*)alloc(sizeof(bf16) * M * Dm);
    bf16* zBb = (bf16*)alloc(sizeof(bf16) * M * Dm);
    bf16* zCb = (bf16*)alloc(sizeof(bf16) * M * Dm);       // decoder input (pre-cast)
    bf16* zencb = (bf16*)alloc(sizeof(bf16) * M * Dm);

    if ((size_t)(wsp - (char*)d_ws) > ws_size) return;

    // ---- one-time prep: weight transpose (batched) + input casts ----
    {
        dim3 bl(32, 8);
        wtrans2_kernel<<<dim3(Dm / 32, Dm / 32, 72), bl, 0, stream>>>(
            enc_W, wtEncW, 24, dec_W, wtDecW, Dm, Dm);
        wtrans2_kernel<<<dim3(FFm / 32, Dm / 32, 12), bl, 0, stream>>>(
            enc_W1, wtEncW1, 6, dec_W1, wtDecW1, Dm, FFm);
        wtrans2_kernel<<<dim3(Dm / 32, FFm / 32, 12), bl, 0, stream>>>(
            enc_W2, wtEncW2, 6, dec_W2, wtDecW2, FFm, Dm);
        cast_kernel<<<2048, 256, 0, stream>>>(in_enc, zAb);
        cast_kernel<<<2048, 256, 0, stream>>>(in_dec, zCb);
    }

    bf16* curB = zAb;
    bf16* othB = zBb;
    auto swapbuf = [&]() { bf16* tb = curB; curB = othB; othB = tb; };

    // self-attention: fused QKV proj (V -> vt transposed), flash, outproj
    auto self_attention = [&](const bf16* src, const bf16* Wt4, const float* b4) {
        gemm_nt<128, 128, EPI_QKV, true, 512, 2, 4><<<dim3(32, 12, 1), 512, 0, stream>>>(
            src, Wt4, b4, qkvbuf, vt, Dm, Dm, Dm, 1024, 1024, 0, 0, 0, 0);
        flash_kernel<<<dim3(64, 8), 256, 0, stream>>>(
            qkvbuf, qkvbuf + 512, vt, ckbuf, 1024, 512, QSCALE);
        gemm_nt<64, 64, EPI_BF16, true, 256, 2, 2><<<dim3(64, 8, 1), 256, 0, stream>>>(
            ckbuf, Wt4 + 3 * DD, b4 + 3 * Dm, projb, nullptr, Dm, 512, Dm, Dm, 0,
            0, 0, 0, 0);
    };

    // cross-attention layer i: Q proj, flash vs precomputed ck6/cv6, outproj
    auto cross_attention = [&](const bf16* src, const bf16* Wt4, const float* b4, int i) {
        gemm_nt<64, 64, EPI_BF16, true, 256, 2, 2><<<dim3(64, 8, 1), 256, 0, stream>>>(
            src, Wt4, b4, qkvbuf, nullptr, Dm, Dm, Dm, 1024, 0, 0, 0, 0, 0);
        flash_kernel<<<dim3(64, 8), 256, 0, stream>>>(
            qkvbuf, ck6 + (long long)i * MD, cv6 + (long long)i * MD, qkvbuf + 512,
            512, 1024, QSCALE);
        gemm_nt<64, 64, EPI_BF16, true, 256, 2, 2><<<dim3(64, 8, 1), 256, 0, stream>>>(
            qkvbuf + 512, Wt4 + 3 * DD, b4 + 3 * Dm, projb, nullptr, Dm, 1024, Dm, Dm, 0,
            0, 0, 0, 0);
    };

    auto ffn = [&](const bf16* src, const bf16* W1t, const float* b1v,
                   const bf16* W2t, const float* b2v) {
        gemm_nt<128, 128, EPI_RELU, true, 512, 2, 4><<<dim3(32, 16, 1), 512, 0, stream>>>(
            src, W1t, b1v, ffnmid, nullptr, Dm, Dm, Dm, FFm, 0, 0, 0, 0, 0);
        gemm_nt<64, 64, EPI_BF16, true, 256, 2, 2><<<dim3(64, 8, 1), 256, 0, stream>>>(
            ffnmid, W2t, b2v, projb, nullptr, FFm, FFm, FFm, Dm, 0, 0, 0, 0, 0);
    };

    // ================= encoder =================
    for (int i = 0; i < Lm; ++i) {
        self_attention(curB, wtEncW + (size_t)i * 4 * DD, enc_b + (size_t)i * 4 * Dm);
        add_ln_kernel<<<1024, 256, 0, stream>>>(
            projb, curB, enc_al + (size_t)(i * 2) * Dm, enc_be + (size_t)(i * 2) * Dm,
            nullptr, othB);
        swapbuf();
        ffn(curB, wtEncW1 + (size_t)i * DFF, enc_b1 + (size_t)i * FFm,
            wtEncW2 + (size_t)i * DFF, enc_b2 + (size_t)i * Dm);
        add_ln_kernel<<<1024, 256, 0, stream>>>(
            projb, curB, enc_al + (size_t)(i * 2 + 1) * Dm, enc_be + (size_t)(i * 2 + 1) * Dm,
            nullptr, othB);
        swapbuf();
    }
    add_ln_kernel<<<1024, 256, 0, stream>>>(nullptr, curB, fin_al, fin_be, nullptr, zencb);

    // Precompute cross K/V for ALL 6 decoder layers in one batched GEMM.
    gemm_nt<128, 128, EPI_QKV, true, 512, 2, 4><<<dim3(32, 8, 6), 512, 0, stream>>>(
        zencb, wtDecW + 5 * DD, dec_b + 5 * Dm, ck6, cv6, Dm, Dm, Dm, 512, 512,
        /*oBz=*/8LL * (long long)DD, /*oCz=*/MD, /*oCvz=*/MD, /*oBiasz=*/8LL * Dm);

    // ================= decoder =================
    curB = zCb; othB = zBb;
    for (int i = 0; i < Lm; ++i) {
        self_attention(curB, wtDecW + (size_t)(i * 2 + 0) * 4 * DD,
                       dec_b + (size_t)(i * 2 + 0) * 4 * Dm);
        add_ln_kernel<<<1024, 256, 0, stream>>>(
            projb, curB, dec_al + (size_t)(i * 3 + 0) * Dm, dec_be + (size_t)(i * 3 + 0) * Dm,
            nullptr, othB);
        if (curB == zCb) { curB = othB; othB = zAb; }
        else swapbuf();
        cross_attention(curB, wtDecW + (size_t)(i * 2 + 1) * 4 * DD,
                        dec_b + (size_t)(i * 2 + 1) * 4 * Dm, i);
        add_ln_kernel<<<1024, 256, 0, stream>>>(
            projb, curB, dec_al + (size_t)(i * 3 + 1) * Dm, dec_be + (size_t)(i * 3 + 1) * Dm,
            nullptr, othB);
        swapbuf();
        ffn(curB, wtDecW1 + (size_t)i * DFF, dec_b1 + (size_t)i * FFm,
            wtDecW2 + (size_t)i * DFF, dec_b2 + (size_t)i * Dm);
        add_ln_kernel<<<1024, 256, 0, stream>>>(
            projb, curB, dec_al + (size_t)(i * 3 + 2) * Dm, dec_be + (size_t)(i * 3 + 2) * Dm,
            nullptr, othB);
        swapbuf();
    }
    add_ln_kernel<<<1024, 256, 0, stream>>>(nullptr, curB, fin_al + Dm, fin_be + Dm,
                                            (float*)d_out, nullptr);
}